// Round 5
// baseline (41574.988 us; speedup 1.0000x reference)
//
#include <hip/hip_runtime.h>
#include <cstdint>
#include <cstddef>

typedef _Float16 f16;
typedef _Float16 f16x8 __attribute__((ext_vector_type(8)));
typedef float f32x4 __attribute__((ext_vector_type(4)));
typedef float f32x2 __attribute__((ext_vector_type(2)));
typedef uint32_t u32x4 __attribute__((ext_vector_type(4)));

#define MFMA_F16(a,b,c) __builtin_amdgcn_mfma_f32_16x16x32_f16((a),(b),(c),0,0,0)

#define NB   256   // recurrence blocks
#define NCLS 16    // barrier / stat classes

__device__ __forceinline__ float sigf(float x){ return 1.f/(1.f + expf(-x)); }

// Write-through stores to the coherence point (no dirty L2 line).
__device__ __forceinline__ void st_wt_f16(f16* p, f16 v){
  asm volatile("global_store_short %0, %1, off sc0 sc1" :: "v"(p), "v"(v) : "memory");
}
__device__ __forceinline__ void st_wt_u32(uint32_t* p, uint32_t v){
  asm volatile("global_store_dword %0, %1, off sc0 sc1" :: "v"(p), "v"(v) : "memory");
}
__device__ __forceinline__ void vm_drain(){ asm volatile("s_waitcnt vmcnt(0)" ::: "memory"); }

// Coherent load of 16 class-partial (s,q) pairs + LN stats.
__device__ __forceinline__ void ln_stats(const float* p, float invn, float& m, float& rs){
  f32x2 v0,v1,v2,v3,v4,v5,v6,v7,v8,v9,v10,v11,v12,v13,v14,v15;
  asm volatile(
    "global_load_dwordx2 %0, %16, off sc0 sc1\n\t"
    "global_load_dwordx2 %1, %16, off offset:256 sc0 sc1\n\t"
    "global_load_dwordx2 %2, %16, off offset:512 sc0 sc1\n\t"
    "global_load_dwordx2 %3, %16, off offset:768 sc0 sc1\n\t"
    "global_load_dwordx2 %4, %16, off offset:1024 sc0 sc1\n\t"
    "global_load_dwordx2 %5, %16, off offset:1280 sc0 sc1\n\t"
    "global_load_dwordx2 %6, %16, off offset:1536 sc0 sc1\n\t"
    "global_load_dwordx2 %7, %16, off offset:1792 sc0 sc1\n\t"
    "global_load_dwordx2 %8, %16, off offset:2048 sc0 sc1\n\t"
    "global_load_dwordx2 %9, %16, off offset:2304 sc0 sc1\n\t"
    "global_load_dwordx2 %10, %16, off offset:2560 sc0 sc1\n\t"
    "global_load_dwordx2 %11, %16, off offset:2816 sc0 sc1\n\t"
    "global_load_dwordx2 %12, %16, off offset:3072 sc0 sc1\n\t"
    "global_load_dwordx2 %13, %16, off offset:3328 sc0 sc1\n\t"
    "global_load_dwordx2 %14, %16, off offset:3584 sc0 sc1\n\t"
    "global_load_dwordx2 %15, %16, off offset:3840 sc0 sc1\n\t"
    "s_waitcnt vmcnt(0)"
    : "=&v"(v0),"=&v"(v1),"=&v"(v2),"=&v"(v3),"=&v"(v4),"=&v"(v5),"=&v"(v6),"=&v"(v7),
      "=&v"(v8),"=&v"(v9),"=&v"(v10),"=&v"(v11),"=&v"(v12),"=&v"(v13),"=&v"(v14),"=&v"(v15)
    : "v"(p) : "memory");
  float s = v0.x+v1.x+v2.x+v3.x+v4.x+v5.x+v6.x+v7.x+v8.x+v9.x+v10.x+v11.x+v12.x+v13.x+v14.x+v15.x;
  float q = v0.y+v1.y+v2.y+v3.y+v4.y+v5.y+v6.y+v7.y+v8.y+v9.y+v10.y+v11.y+v12.y+v13.y+v14.y+v15.y;
  m = s*invn; rs = rsqrtf(q*invn - m*m + 1e-5f);
}

// Coherent load of 8 chunks (kk*128B) x 2 dwordx4 from one row pointer.
__device__ __forceinline__ void ld_co16_1p(const uint32_t* p, u32x4* r){
  asm volatile(
    "global_load_dwordx4 %0, %16, off sc0 sc1\n\t"
    "global_load_dwordx4 %1, %16, off offset:16 sc0 sc1\n\t"
    "global_load_dwordx4 %2, %16, off offset:128 sc0 sc1\n\t"
    "global_load_dwordx4 %3, %16, off offset:144 sc0 sc1\n\t"
    "global_load_dwordx4 %4, %16, off offset:256 sc0 sc1\n\t"
    "global_load_dwordx4 %5, %16, off offset:272 sc0 sc1\n\t"
    "global_load_dwordx4 %6, %16, off offset:384 sc0 sc1\n\t"
    "global_load_dwordx4 %7, %16, off offset:400 sc0 sc1\n\t"
    "global_load_dwordx4 %8, %16, off offset:512 sc0 sc1\n\t"
    "global_load_dwordx4 %9, %16, off offset:528 sc0 sc1\n\t"
    "global_load_dwordx4 %10, %16, off offset:640 sc0 sc1\n\t"
    "global_load_dwordx4 %11, %16, off offset:656 sc0 sc1\n\t"
    "global_load_dwordx4 %12, %16, off offset:768 sc0 sc1\n\t"
    "global_load_dwordx4 %13, %16, off offset:784 sc0 sc1\n\t"
    "global_load_dwordx4 %14, %16, off offset:896 sc0 sc1\n\t"
    "global_load_dwordx4 %15, %16, off offset:912 sc0 sc1\n\t"
    "s_waitcnt vmcnt(0)"
    : "=&v"(r[0]),"=&v"(r[1]),"=&v"(r[2]),"=&v"(r[3]),"=&v"(r[4]),"=&v"(r[5]),"=&v"(r[6]),"=&v"(r[7]),
      "=&v"(r[8]),"=&v"(r[9]),"=&v"(r[10]),"=&v"(r[11]),"=&v"(r[12]),"=&v"(r[13]),"=&v"(r[14]),"=&v"(r[15])
    : "v"(p) : "memory");
}
// Coherent load of 4 chunks x 2 dwordx4 from each of two row pointers.
__device__ __forceinline__ void ld_co16_2p(const uint32_t* p0, const uint32_t* p1, u32x4* r){
  asm volatile(
    "global_load_dwordx4 %0, %16, off sc0 sc1\n\t"
    "global_load_dwordx4 %1, %16, off offset:16 sc0 sc1\n\t"
    "global_load_dwordx4 %2, %16, off offset:128 sc0 sc1\n\t"
    "global_load_dwordx4 %3, %16, off offset:144 sc0 sc1\n\t"
    "global_load_dwordx4 %4, %16, off offset:256 sc0 sc1\n\t"
    "global_load_dwordx4 %5, %16, off offset:272 sc0 sc1\n\t"
    "global_load_dwordx4 %6, %16, off offset:384 sc0 sc1\n\t"
    "global_load_dwordx4 %7, %16, off offset:400 sc0 sc1\n\t"
    "global_load_dwordx4 %8, %17, off sc0 sc1\n\t"
    "global_load_dwordx4 %9, %17, off offset:16 sc0 sc1\n\t"
    "global_load_dwordx4 %10, %17, off offset:128 sc0 sc1\n\t"
    "global_load_dwordx4 %11, %17, off offset:144 sc0 sc1\n\t"
    "global_load_dwordx4 %12, %17, off offset:256 sc0 sc1\n\t"
    "global_load_dwordx4 %13, %17, off offset:272 sc0 sc1\n\t"
    "global_load_dwordx4 %14, %17, off offset:384 sc0 sc1\n\t"
    "global_load_dwordx4 %15, %17, off offset:400 sc0 sc1\n\t"
    "s_waitcnt vmcnt(0)"
    : "=&v"(r[0]),"=&v"(r[1]),"=&v"(r[2]),"=&v"(r[3]),"=&v"(r[4]),"=&v"(r[5]),"=&v"(r[6]),"=&v"(r[7]),
      "=&v"(r[8]),"=&v"(r[9]),"=&v"(r[10]),"=&v"(r[11]),"=&v"(r[12]),"=&v"(r[13]),"=&v"(r[14]),"=&v"(r[15])
    : "v"(p0),"v"(p1) : "memory");
}

// Reconstruct one h A-fragment from 8 packed (c,o) pairs + per-row LN stats +
// per-unit (g,b) staged in LDS. h = o * tanh((c*rs - m*rs)*g + b).
__device__ __forceinline__ f16x8 mk_h(u32x4 wa, u32x4 wb, float rs, float nmrs,
                                      const f16* gcp, const f16* bcp){
  f16x8 g8 = *(const f16x8*)gcp;
  f16x8 b8 = *(const f16x8*)bcp;
  f16x8 r;
  #pragma unroll
  for (int j = 0; j < 8; ++j){
    union { uint32_t u; f16 h[2]; } cv;
    cv.u = (j < 4) ? wa[j] : wb[j-4];
    float c = (float)cv.h[0], o = (float)cv.h[1];
    float arg = fmaf(fmaf(c, rs, nmrs), (float)g8[j], (float)b8[j]);
    float e = exp2f(arg * 2.885390081777927f);              // e^{2*arg}
    float rc = __builtin_amdgcn_rcpf(e + 1.f);
    r[j] = (f16)(o * fmaf(-2.f, rc, 1.f));                  // o*tanh(arg)
  }
  return r;
}

// ---------------------------------------------------------------------------
// Generic f32 (K,N) -> f16 (N, dstStride) transpose with row offset
// ---------------------------------------------------------------------------
__global__ __launch_bounds__(256) void k_transpose_f16(const float* __restrict__ src,
    f16* __restrict__ dst, int K, int N, int dstStride, int dstOff){
  const int n0 = blockIdx.x*32, k0 = blockIdx.y*32, tid = threadIdx.x;
  __shared__ float tl[32][33];
  #pragma unroll
  for (int rep = 0; rep < 4; ++rep){
    int e = rep*256 + tid; int i = e >> 5, j = e & 31;
    int k = k0 + i, n = n0 + j;
    tl[i][j] = (k < K && n < N) ? src[(size_t)k*N + n] : 0.f;
  }
  __syncthreads();
  #pragma unroll
  for (int rep = 0; rep < 4; ++rep){
    int e = rep*256 + tid; int i2 = e & 31, j2 = e >> 5;
    int n = n0 + j2, k = k0 + i2;
    if (k < K && n < N) dst[(size_t)n*dstStride + dstOff + k] = (f16)tl[i2][j2];
  }
}

// ---------------------------------------------------------------------------
// Prenet: one block per t; pre[t] = relu(relu(dec[t-1]@w1)@w2) -> cellin[:,0:256]
// ---------------------------------------------------------------------------
__global__ __launch_bounds__(256) void k_prenet(const float* __restrict__ dec,
    const float* __restrict__ w1, const float* __restrict__ w2, f16* __restrict__ cellin){
  const int t = blockIdx.x, tid = threadIdx.x;
  __shared__ float sin_[32][81];
  __shared__ f16   w1T[256][88];
  __shared__ float x1s[32][260];
  __shared__ f16   w2c[256][72];
  __shared__ f16   xo[32][256];
  for (int e = tid; e < 32*80; e += 256){
    int i = e/80, m = e - i*80;
    sin_[i][m] = (t == 0) ? 0.f : dec[(size_t)i*61440 + (size_t)m*768 + (t-1)];
  }
  for (int e = tid; e < 80*256; e += 256){ int m = e >> 8, j = e & 255; w1T[j][m] = (f16)w1[e]; }
  __syncthreads();
  const int j = tid;
  for (int i = 0; i < 32; ++i){
    float a = 0.f;
    #pragma unroll
    for (int m8 = 0; m8 < 10; ++m8){
      f16x8 wvv = *(const f16x8*)&w1T[j][m8*8];
      #pragma unroll
      for (int l = 0; l < 8; ++l) a += (float)wvv[l] * sin_[i][m8*8 + l];
    }
    x1s[i][j] = fmaxf(a, 0.f);
  }
  __syncthreads();
  float acc2[32];
  #pragma unroll
  for (int i = 0; i < 32; ++i) acc2[i] = 0.f;
  for (int c = 0; c < 4; ++c){
    for (int e = tid; e < 64*256; e += 256){
      int kl = e >> 8, jj = e & 255;
      w2c[jj][kl] = (f16)w2[(size_t)(c*64 + kl)*256 + jj];
    }
    __syncthreads();
    f16x8 wv8[8];
    #pragma unroll
    for (int k8 = 0; k8 < 8; ++k8) wv8[k8] = *(const f16x8*)&w2c[j][k8*8];
    for (int i = 0; i < 32; ++i){
      float a = 0.f;
      #pragma unroll
      for (int k8 = 0; k8 < 8; ++k8)
        #pragma unroll
        for (int l = 0; l < 8; ++l) a += (float)wv8[k8][l]*x1s[i][c*64 + k8*8 + l];
      acc2[i] += a;
    }
    __syncthreads();
  }
  for (int i = 0; i < 32; ++i) xo[i][j] = (f16)fmaxf(acc2[i], 0.f);
  __syncthreads();
  for (int e = tid; e < 32*256; e += 256){
    int i = e >> 8, jj = e & 255;
    cellin[((size_t)t*32 + i)*800 + jj] = xo[i][jj];
  }
}

// ---------------------------------------------------------------------------
// dur -> cellin[:,256:800] (f16)
// ---------------------------------------------------------------------------
__global__ __launch_bounds__(256) void k_durfill(const float* __restrict__ dur, f16* __restrict__ cellin){
  const int t = blockIdx.x, tid = threadIdx.x;
  for (int e = tid; e < 32*544; e += 256){
    int b = e / 544, c = e - b*544;
    cellin[((size_t)t*32 + b)*800 + 256 + c] = (f16)dur[(size_t)b*417792 + (size_t)t*544 + c];
  }
}

// ---------------------------------------------------------------------------
__global__ __launch_bounds__(256) void k_ws_report(float* __restrict__ out, int n, float val){
  int i = blockIdx.x*256 + threadIdx.x;
  if (i < n) out[i] = val;
}

// ---------------------------------------------------------------------------
// Split-phase grid barrier (monotonic counters; sc-coherent data traffic means
// no cache fences needed — only ordering).
// ---------------------------------------------------------------------------
__device__ __forceinline__ void gbar_arrive(unsigned* __restrict__ ctrs, int cls, int tid){
  vm_drain();
  __syncthreads();
  if (tid == 0)
    __hip_atomic_fetch_add(ctrs + cls*32, 1u, __ATOMIC_RELAXED, __HIP_MEMORY_SCOPE_AGENT);
}
__device__ __forceinline__ void gbar_wait(unsigned* __restrict__ ctrs, unsigned target, int tid){
  if (tid < NCLS){
    while (__hip_atomic_load(ctrs + tid*32, __ATOMIC_RELAXED, __HIP_MEMORY_SCOPE_AGENT) < target)
      __builtin_amdgcn_s_sleep(1);
  }
  __syncthreads();
}

// ---------------------------------------------------------------------------
// Persistent recurrence, 4 barriers/step. Owners publish (c, sig(o)) as packed
// f16 pairs with the c-stats barrier; consumers rebuild h per MFMA fragment
// (tanh on the fly, per-unit g/b in LDS). Split-phase barriers hide the
// fragment prefetch/tanh in the barrier waits.
// ---------------------------------------------------------------------------
__global__ __launch_bounds__(512, 2) void k_recurrence(
    const f16* __restrict__ cellin, const f16* __restrict__ wxT1,
    const f16* __restrict__ whT1, const f16* __restrict__ w2T,
    f16* __restrict__ H2all, uint32_t* __restrict__ co1, uint32_t* __restrict__ co2,
    float* __restrict__ sacc, unsigned* __restrict__ ctrs,
    const float* __restrict__ b1,
    const float* __restrict__ g1, const float* __restrict__ bn1,
    const float* __restrict__ gc1v, const float* __restrict__ bc1v,
    const float* __restrict__ g2, const float* __restrict__ bn2,
    const float* __restrict__ gc2v, const float* __restrict__ bc2v,
    const float* __restrict__ b2)
{
  const int tid = threadIdx.x, blk = blockIdx.x;
  const int lane = tid & 63, wv = tid >> 6;
  const int r16 = lane & 15, quad = lane >> 4;
  const int ub0 = blk << 2;
  const int cls = blk & (NCLS-1);
  const int colg = ((r16 >> 2) << 10) + ub0 + (r16 & 3);  // B-frag gate-column
  f16x8 b1f[4], b2f[8];
  #pragma unroll
  for (int kk = 0; kk < 4; ++kk)
    b1f[kk] = *(const f16x8*)(whT1 + (size_t)colg*1024 + wv*128 + kk*32 + quad*8);
  #pragma unroll
  for (int kk = 0; kk < 8; ++kk)
    b2f[kk] = *(const f16x8*)(w2T + (size_t)colg*2048 + wv*256 + kk*32 + quad*8);

  // wx1 block-slice into LDS in exact B-fragment order: [chunk][quad][p][8]
  __shared__ f16 swx[25*4*16*8];
  for (int idx = tid; idx < 1600; idx += 512){
    int chunk = idx >> 6, q = (idx >> 4) & 3, p = idx & 15;
    int cg = ((p >> 2) << 10) + ub0 + (p & 3);
    *(f16x8*)(swx + idx*8) = *(const f16x8*)(wxT1 + (size_t)cg*800 + chunk*32 + q*8);
  }
  // Per-unit LN(c) affine params in LDS (f16), for consumer-side h rebuild.
  __shared__ f16 sgc1[1024], sbc1[1024], sgc2[1024], sbc2[1024];
  for (int u = tid; u < 1024; u += 512){
    sgc1[u] = (f16)gc1v[u]; sbc1[u] = (f16)bc1v[u];
    sgc2[u] = (f16)gc2v[u]; sbc2[u] = (f16)bc2v[u];
  }

  const int ul = tid >> 5, rb = tid & 31;          // owners: tid < 128
  float p1g[4], p1b[4], p2g[4], p2b[4], gC1=0.f,bC1=0.f,gC2=0.f,bC2=0.f;
  if (tid < 128){
    #pragma unroll
    for (int g = 0; g < 4; ++g){
      int cg = (g<<10) + ub0 + ul;
      p1g[g]=g1[cg]; p1b[g]=bn1[cg]; p2g[g]=g2[cg]; p2b[g]=bn2[cg];
    }
    gC1 = gc1v[ub0+ul]; bC1 = bc1v[ub0+ul]; gC2 = gc2v[ub0+ul]; bC2 = bc2v[ub0+ul];
  }
  const int zb = tid >> 4, zc = tid & 15;          // z-finish: (row, col_local)
  const int zcolg = ((zc >> 2) << 10) + ub0 + (zc & 3);
  const float bias1 = b1[zcolg];
  const float bias2 = b2[zcolg];
  float c1 = 0.f, c2 = 0.f, o1 = 0.f, o2 = 0.f;

  __shared__ float zred[8][32][17];
  __shared__ float zfin[32][17];
  __shared__ float mst[32], vst[32];
  __shared__ float mc1s[32], vc1s[32], mc2s[32], vc2s[32];
  __shared__ float csA[4][32], csQ[4][32];
  unsigned nbar = 0;

  f16x8 hA[8];    // h1_{t-1} A-frags for phase A (kk 0..3 row r16; 4..7 row 16+r16)
  f16x8 hC[16];   // h2_{t-1} A-frags for phase C (wv>=4 only; kk 0..7 / 8..15)
  #pragma unroll
  for (int i = 0; i < 8; ++i) hA[i] = (f16x8)(f16)0.f;
  #pragma unroll
  for (int i = 0; i < 16; ++i) hC[i] = (f16x8)(f16)0.f;
  __syncthreads();   // LDS ready

  for (int t = 0; t < 768; ++t){
    const f16* CIt = cellin + (size_t)t*32*800;
    // =============== PHASE A: z1 = x_t@wx1 + h1_{t-1}@wh1 ===============
    if (t > 0 && wv == 7 && lane < 32){           // c2-stats of t-1 (for h2 rebuild)
      float m, rs;
      ln_stats(sacc + (((size_t)(t-1)*4 + 3)*NCLS)*64 + 2*lane, 1.f/1024.f, m, rs);
      mc2s[lane] = m; vc2s[lane] = rs;
    }
    f32x4 acc0 = {0.f,0.f,0.f,0.f}, acc1 = {0.f,0.f,0.f,0.f};
    {
      const int cbeg = (wv == 0) ? 0 : (wv*3 + 1);
      const int cend = wv*3 + 4;
      for (int c = cbeg; c < cend; ++c){
        f16x8 a0 = *(const f16x8*)(CIt + (size_t)r16*800 + c*32 + quad*8);
        f16x8 a1 = *(const f16x8*)(CIt + (size_t)(16+r16)*800 + c*32 + quad*8);
        f16x8 bx = *(const f16x8*)(swx + (((c*4 + quad)*16 + r16) << 3));
        acc0 = MFMA_F16(a0, bx, acc0);
        acc1 = MFMA_F16(a1, bx, acc1);
      }
    }
    #pragma unroll
    for (int kk = 0; kk < 4; ++kk){
      acc0 = MFMA_F16(hA[kk],   b1f[kk], acc0);
      acc1 = MFMA_F16(hA[4+kk], b1f[kk], acc1);
    }
    #pragma unroll
    for (int reg = 0; reg < 4; ++reg){
      zred[wv][(quad<<2)+reg][r16]    = acc0[reg];
      zred[wv][16+(quad<<2)+reg][r16] = acc1[reg];
    }
    __syncthreads();                               // also publishes mc2s/vc2s
    {
      float z = bias1;
      #pragma unroll
      for (int w = 0; w < 8; ++w) z += zred[w][zb][zc];
      zfin[zb][zc] = z;
      float s = z, q = z*z;
      s += __shfl_down(s, 8); q += __shfl_down(q, 8);
      s += __shfl_down(s, 4); q += __shfl_down(q, 4);
      s += __shfl_down(s, 2); q += __shfl_down(q, 2);
      s += __shfl_down(s, 1); q += __shfl_down(q, 1);
      if (zc == 0){
        float* a = sacc + (((size_t)t*4 + 0)*NCLS + cls)*64;
        atomicAdd(a + 2*zb, s); atomicAdd(a + 2*zb + 1, q);
      }
    }
    if (t > 0 && tid < 128){                       // h2_{t-1} -> HBM for k_proj (off-chain)
      float rs = vc2s[rb];
      float arg = fmaf(fmaf(c2, rs, -mc2s[rb]*rs), gC2, bC2);
      float e = exp2f(arg * 2.885390081777927f);
      float h = o2 * fmaf(-2.f, __builtin_amdgcn_rcpf(e + 1.f), 1.f);
      st_wt_f16(H2all + (size_t)t*32768 + rb*1024 + ub0 + ul, (f16)h);
    }
    gbar_arrive(ctrs, cls, tid);
    // FILLER (hidden in wait): rebuild h2_{t-1} frags for phase C (wv>=4)
    if (wv >= 4){
      if (t > 0){
        const int kb = (wv-4)*256 + quad*8;
        float rs0 = vc2s[r16],   nm0 = -mc2s[r16]*rs0;
        float rs1 = vc2s[16+r16], nm1 = -mc2s[16+r16]*rs1;
        u32x4 raw[16];
        ld_co16_1p(co2 + r16*1024 + kb, raw);
        #pragma unroll
        for (int kk = 0; kk < 8; ++kk)
          hC[kk] = mk_h(raw[2*kk], raw[2*kk+1], rs0, nm0, sgc2+kb+kk*32, sbc2+kb+kk*32);
        ld_co16_1p(co2 + (size_t)(16+r16)*1024 + kb, raw);
        #pragma unroll
        for (int kk = 0; kk < 8; ++kk)
          hC[8+kk] = mk_h(raw[2*kk], raw[2*kk+1], rs1, nm1, sgc2+kb+kk*32, sbc2+kb+kk*32);
      }
    }
    gbar_wait(ctrs, (NB/NCLS)*(++nbar), tid);
    // =============== PHASE B: LN1 -> gates -> c1; publish (c1,o1) ===============
    if (tid < 32){
      float m, rs;
      ln_stats(sacc + (((size_t)t*4 + 0)*NCLS)*64 + 2*tid, 1.f/4096.f, m, rs);
      mst[tid] = m; vst[tid] = rs;
    }
    __syncthreads();
    if (tid < 128){
      const float m = mst[rb], rs = vst[rb];
      const float zi = (zfin[rb][ul]      - m)*rs*p1g[0] + p1b[0];
      const float zf = (zfin[rb][4+ul]    - m)*rs*p1g[1] + p1b[1];
      const float zg = (zfin[rb][8+ul]    - m)*rs*p1g[2] + p1b[2];
      const float zo = (zfin[rb][12+ul]   - m)*rs*p1g[3] + p1b[3];
      c1 = sigf(zf)*c1 + sigf(zi)*tanhf(zg);
      o1 = sigf(zo);
      union { uint32_t u; f16 h[2]; } pv;
      pv.h[0] = (f16)c1; pv.h[1] = (f16)o1;
      st_wt_u32(co1 + rb*1024 + ub0 + ul, pv.u);
      csA[ul][rb] = c1; csQ[ul][rb] = c1*c1;
    }
    __syncthreads();
    if (tid < 32){
      float s = csA[0][tid]+csA[1][tid]+csA[2][tid]+csA[3][tid];
      float q = csQ[0][tid]+csQ[1][tid]+csQ[2][tid]+csQ[3][tid];
      float* a = sacc + (((size_t)t*4 + 1)*NCLS + cls)*64;
      atomicAdd(a + 2*tid, s); atomicAdd(a + 2*tid + 1, q);
    }
    gbar_arrive(ctrs, cls, tid);
    gbar_wait(ctrs, (NB/NCLS)*(++nbar), tid);
    // =============== PHASE C: z2 = h1_t@w2x + h2_{t-1}@w2h ===============
    u32x4 rawc[16];
    if (wv < 4)
      ld_co16_1p(co1 + r16*1024 + wv*256 + quad*8, rawc);   // row r16, overlaps ln_stats
    if (wv == 7 && lane < 32){
      float m, rs;
      ln_stats(sacc + (((size_t)t*4 + 1)*NCLS)*64 + 2*lane, 1.f/1024.f, m, rs);
      mc1s[lane] = m; vc1s[lane] = rs;
    }
    __syncthreads();                               // mc1s/vc1s ready
    acc0 = (f32x4){0.f,0.f,0.f,0.f}; acc1 = (f32x4){0.f,0.f,0.f,0.f};
    if (wv < 4){
      const int kb = wv*256 + quad*8;
      float rs0 = vc1s[r16],    nm0 = -mc1s[r16]*rs0;
      float rs1 = vc1s[16+r16], nm1 = -mc1s[16+r16]*rs1;
      #pragma unroll
      for (int kk = 0; kk < 8; ++kk){
        f16x8 a = mk_h(rawc[2*kk], rawc[2*kk+1], rs0, nm0, sgc1+kb+kk*32, sbc1+kb+kk*32);
        acc0 = MFMA_F16(a, b2f[kk], acc0);
      }
      ld_co16_1p(co1 + (size_t)(16+r16)*1024 + kb, rawc);
      #pragma unroll
      for (int kk = 0; kk < 8; ++kk){
        f16x8 a = mk_h(rawc[2*kk], rawc[2*kk+1], rs1, nm1, sgc1+kb+kk*32, sbc1+kb+kk*32);
        acc1 = MFMA_F16(a, b2f[kk], acc1);
      }
    } else {
      #pragma unroll
      for (int kk = 0; kk < 8; ++kk){
        acc0 = MFMA_F16(hC[kk],   b2f[kk], acc0);
        acc1 = MFMA_F16(hC[8+kk], b2f[kk], acc1);
      }
    }
    #pragma unroll
    for (int reg = 0; reg < 4; ++reg){
      zred[wv][(quad<<2)+reg][r16]    = acc0[reg];
      zred[wv][16+(quad<<2)+reg][r16] = acc1[reg];
    }
    __syncthreads();
    {
      float z = bias2;
      #pragma unroll
      for (int w = 0; w < 8; ++w) z += zred[w][zb][zc];
      zfin[zb][zc] = z;
      float s = z, q = z*z;
      s += __shfl_down(s, 8); q += __shfl_down(q, 8);
      s += __shfl_down(s, 4); q += __shfl_down(q, 4);
      s += __shfl_down(s, 2); q += __shfl_down(q, 2);
      s += __shfl_down(s, 1); q += __shfl_down(q, 1);
      if (zc == 0){
        float* a = sacc + (((size_t)t*4 + 2)*NCLS + cls)*64;
        atomicAdd(a + 2*zb, s); atomicAdd(a + 2*zb + 1, q);
      }
    }
    gbar_arrive(ctrs, cls, tid);
    // FILLER: rebuild h1_t frags for next phase A (all waves; stats still in LDS)
    {
      const int kb = wv*128 + quad*8;
      float rs0 = vc1s[r16],    nm0 = -mc1s[r16]*rs0;
      float rs1 = vc1s[16+r16], nm1 = -mc1s[16+r16]*rs1;
      u32x4 raw2[16];
      ld_co16_2p(co1 + r16*1024 + kb, co1 + (size_t)(16+r16)*1024 + kb, raw2);
      #pragma unroll
      for (int kk = 0; kk < 4; ++kk){
        hA[kk]   = mk_h(raw2[2*kk],   raw2[2*kk+1],   rs0, nm0, sgc1+kb+kk*32, sbc1+kb+kk*32);
        hA[4+kk] = mk_h(raw2[8+2*kk], raw2[9+2*kk],   rs1, nm1, sgc1+kb+kk*32, sbc1+kb+kk*32);
      }
    }
    gbar_wait(ctrs, (NB/NCLS)*(++nbar), tid);
    // =============== PHASE D: LN2 -> gates -> c2; publish (c2,o2) ===============
    if (tid < 32){
      float m, rs;
      ln_stats(sacc + (((size_t)t*4 + 2)*NCLS)*64 + 2*tid, 1.f/4096.f, m, rs);
      mst[tid] = m; vst[tid] = rs;
    }
    __syncthreads();
    if (tid < 128){
      const float m = mst[rb], rs = vst[rb];
      const float zi = (zfin[rb][ul]      - m)*rs*p2g[0] + p2b[0];
      const float zf = (zfin[rb][4+ul]    - m)*rs*p2g[1] + p2b[1];
      const float zg = (zfin[rb][8+ul]    - m)*rs*p2g[2] + p2b[2];
      const float zo = (zfin[rb][12+ul]   - m)*rs*p2g[3] + p2b[3];
      c2 = sigf(zf)*c2 + sigf(zi)*tanhf(zg);
      o2 = sigf(zo);
      union { uint32_t u; f16 h[2]; } pv;
      pv.h[0] = (f16)c2; pv.h[1] = (f16)o2;
      st_wt_u32(co2 + rb*1024 + ub0 + ul, pv.u);
      csA[ul][rb] = c2; csQ[ul][rb] = c2*c2;
    }
    __syncthreads();
    if (tid < 32){
      float s = csA[0][tid]+csA[1][tid]+csA[2][tid]+csA[3][tid];
      float q = csQ[0][tid]+csQ[1][tid]+csQ[2][tid]+csQ[3][tid];
      float* a = sacc + (((size_t)t*4 + 3)*NCLS + cls)*64;
      atomicAdd(a + 2*tid, s); atomicAdd(a + 2*tid + 1, q);
    }
    gbar_arrive(ctrs, cls, tid);
    gbar_wait(ctrs, (NB/NCLS)*(++nbar), tid);
  }
  // Epilogue: h2_767 -> H2all[768]
  if (wv == 7 && lane < 32){
    float m, rs;
    ln_stats(sacc + (((size_t)767*4 + 3)*NCLS)*64 + 2*lane, 1.f/1024.f, m, rs);
    mc2s[lane] = m; vc2s[lane] = rs;
  }
  __syncthreads();
  if (tid < 128){
    float rs = vc2s[rb];
    float arg = fmaf(fmaf(c2, rs, -mc2s[rb]*rs), gC2, bC2);
    float e = exp2f(arg * 2.885390081777927f);
    float h = o2 * fmaf(-2.f, __builtin_amdgcn_rcpf(e + 1.f), 1.f);
    st_wt_f16(H2all + (size_t)768*32768 + rb*1024 + ub0 + ul, (f16)h);
  }
}

// ---------------------------------------------------------------------------
// out[b][m][t] = [h2_t ; dur_t] @ proj_w + proj_b   (one block per t)
// ---------------------------------------------------------------------------
__global__ __launch_bounds__(256) void k_proj(const f16* __restrict__ H2all, const f16* __restrict__ cellin,
    const f16* __restrict__ projT, const float* __restrict__ projb, float* __restrict__ out){
  const int t = blockIdx.x, tid = threadIdx.x;
  const int lane = tid & 63, wv = tid >> 6;
  const int r16 = lane & 15, quad = lane >> 4;
  __shared__ float pred[4][32][84];
  f32x4 acc[2][5] = {};
  const f16* H2 = H2all + (size_t)(t+1)*32768;
  const f16* CI = cellin + (size_t)t*32*800;
  const int kbeg = wv*13;
  const int kend = (wv == 3) ? 49 : (kbeg + 13);
  for (int ks = kbeg; ks < kend; ++ks){
    const int k0 = ks*32 + quad*8;
    f16x8 a0, a1;
    if (ks < 32){
      a0 = *(const f16x8*)(H2 + r16*1024 + k0);
      a1 = *(const f16x8*)(H2 + (16+r16)*1024 + k0);
    } else {
      a0 = *(const f16x8*)(CI + r16*800 + 256 + (k0 - 1024));
      a1 = *(const f16x8*)(CI + (16+r16)*800 + 256 + (k0 - 1024));
    }
    f16x8 bf[5];
    #pragma unroll
    for (int nt = 0; nt < 5; ++nt)
      bf[nt] = *(const f16x8*)(projT + (size_t)(nt*16 + r16)*1568 + k0);
    #pragma unroll
    for (int nt = 0; nt < 5; ++nt){
      acc[0][nt] = MFMA_F16(a0, bf[nt], acc[0][nt]);
      acc[1][nt] = MFMA_F16(a1, bf[nt], acc[1][nt]);
    }
  }
  #pragma unroll
  for (int mt = 0; mt < 2; ++mt)
    #pragma unroll
    for (int nt = 0; nt < 5; ++nt)
      #pragma unroll
      for (int reg = 0; reg < 4; ++reg)
        pred[wv][mt*16 + quad*4 + reg][nt*16 + r16] = acc[mt][nt][reg];
  __syncthreads();
  for (int e = tid; e < 2560; e += 256){
    int m = e >> 5, b = e & 31;
    float v = pred[0][b][m] + pred[1][b][m] + pred[2][b][m] + pred[3][b][m] + projb[m];
    out[(size_t)b*61440 + (size_t)m*768 + t] = v;
  }
}

// ---------------------------------------------------------------------------
extern "C" void kernel_launch(void* const* d_in, const int* in_sizes, int n_in,
                              void* d_out, int out_size, void* d_ws, size_t ws_size,
                              hipStream_t stream)
{
  const float* duration = (const float*)d_in[0];
  const float* decoder  = (const float*)d_in[1];
  const float* pre_w1   = (const float*)d_in[3];
  const float* pre_w2   = (const float*)d_in[4];
  const float* rnn1_wx  = (const float*)d_in[5];
  const float* rnn1_wh  = (const float*)d_in[6];
  const float* rnn1_b   = (const float*)d_in[7];
  const float* rnn1_g   = (const float*)d_in[8];
  const float* rnn1_bn  = (const float*)d_in[9];
  const float* rnn1_gc  = (const float*)d_in[10];
  const float* rnn1_bc  = (const float*)d_in[11];
  const float* rnn2_wx  = (const float*)d_in[12];
  const float* rnn2_wh  = (const float*)d_in[13];
  const float* rnn2_b   = (const float*)d_in[14];
  const float* rnn2_g   = (const float*)d_in[15];
  const float* rnn2_bn  = (const float*)d_in[16];
  const float* rnn2_gc  = (const float*)d_in[17];
  const float* rnn2_bc  = (const float*)d_in[18];
  const float* proj_w   = (const float*)d_in[19];
  const float* proj_b   = (const float*)d_in[20];
  float* out = (float*)d_out;

  char* w = (char*)d_ws;
  f16* cellin = (f16*)w;      w += (size_t)24576*800*2;
  f16* wxT1   = (f16*)w;      w += (size_t)4096*800*2;
  f16* whT1   = (f16*)w;      w += (size_t)4096*1024*2;
  f16* w2T    = (f16*)w;      w += (size_t)4096*2048*2;
  f16* projT  = (f16*)w;      w += 262144;
  f16* H2all  = (f16*)w;      w += (size_t)769*32768*2;
  uint32_t* co1 = (uint32_t*)w; w += (size_t)32*1024*4;
  uint32_t* co2 = (uint32_t*)w; w += (size_t)32*1024*4;
  float* sacc = (float*)w;    w += (size_t)768*4*16*64*4;
  unsigned* ctrs = (unsigned*)w; w += 2048;
  const size_t need = (size_t)((char*)w - (char*)d_ws);
  if (ws_size < need){
    k_ws_report<<<(out_size + 255)/256, 256, 0, stream>>>(out, out_size, (float)(ws_size >> 20));
    return;
  }

  (void)hipMemsetAsync(sacc, 0, (size_t)768*4*16*64*4, stream);
  (void)hipMemsetAsync(ctrs, 0, 2048, stream);
  (void)hipMemsetAsync(H2all, 0, 65536, stream);

  k_transpose_f16<<<dim3(4096/32, 25), 256, 0, stream>>>(rnn1_wx, wxT1, 800, 4096, 800, 0);
  k_transpose_f16<<<dim3(4096/32, 32), 256, 0, stream>>>(rnn1_wh, whT1, 1024, 4096, 1024, 0);
  k_transpose_f16<<<dim3(4096/32, 32), 256, 0, stream>>>(rnn2_wx, w2T, 1024, 4096, 2048, 0);
  k_transpose_f16<<<dim3(4096/32, 32), 256, 0, stream>>>(rnn2_wh, w2T, 1024, 4096, 2048, 1024);
  k_transpose_f16<<<dim3(3, 49), 256, 0, stream>>>(proj_w, projT, 1568, 80, 1568, 0);
  k_prenet<<<768, 256, 0, stream>>>(decoder, pre_w1, pre_w2, cellin);
  k_durfill<<<768, 256, 0, stream>>>(duration, cellin);
  k_recurrence<<<NB, 512, 0, stream>>>(cellin, wxT1, whT1, w2T, H2all, co1, co2, sacc, ctrs,
      rnn1_b, rnn1_g, rnn1_bn, rnn1_gc, rnn1_bc, rnn2_g, rnn2_bn, rnn2_gc, rnn2_bc, rnn2_b);
  k_proj<<<768, 256, 0, stream>>>(H2all, cellin, projT, proj_b, out);
}

// Round 6
// 15249.171 us; speedup vs baseline: 2.7264x; 2.7264x over previous
//
#include <hip/hip_runtime.h>
#include <cstdint>
#include <cstddef>

typedef _Float16 f16;
typedef _Float16 f16x8 __attribute__((ext_vector_type(8)));
typedef float f32x4 __attribute__((ext_vector_type(4)));
typedef float f32x2 __attribute__((ext_vector_type(2)));

#define MFMA_F16(a,b,c) __builtin_amdgcn_mfma_f32_16x16x32_f16((a),(b),(c),0,0,0)

#define NCLS 16
// counter sets
#define CT_A1 0
#define CT_B1 1
#define CT_H1 2
#define CT_A2 3
#define CT_B2 4
#define CT_H2 5
#define CT_C  6

__device__ __forceinline__ float sigf(float x){ return 1.f/(1.f + expf(-x)); }

__device__ __forceinline__ void st_wt_f16(f16* p, f16 v){
  asm volatile("global_store_short %0, %1, off sc0 sc1" :: "v"(p), "v"(v) : "memory");
}
__device__ __forceinline__ void vm_drain(){ asm volatile("s_waitcnt vmcnt(0)" ::: "memory"); }

__device__ __forceinline__ void bar_arrive(unsigned* c){
  __hip_atomic_fetch_add(c, 1u, __ATOMIC_RELAXED, __HIP_MEMORY_SCOPE_AGENT);
}
__device__ __forceinline__ void bar_poll(const unsigned* ctrs, int set, int tid, unsigned target){
  if (tid < NCLS){
    const unsigned* p = ctrs + (set*NCLS + tid)*16;
    while (__hip_atomic_load(p, __ATOMIC_RELAXED, __HIP_MEMORY_SCOPE_AGENT) < target)
      __builtin_amdgcn_s_sleep(1);
  }
}

// Coherent load of 16 class-partial (s,q) pairs + LN stats.
__device__ __forceinline__ void ln_stats(const float* p, float invn, float& m, float& rs){
  f32x2 v0,v1,v2,v3,v4,v5,v6,v7,v8,v9,v10,v11,v12,v13,v14,v15;
  asm volatile(
    "global_load_dwordx2 %0, %16, off sc0 sc1\n\t"
    "global_load_dwordx2 %1, %16, off offset:256 sc0 sc1\n\t"
    "global_load_dwordx2 %2, %16, off offset:512 sc0 sc1\n\t"
    "global_load_dwordx2 %3, %16, off offset:768 sc0 sc1\n\t"
    "global_load_dwordx2 %4, %16, off offset:1024 sc0 sc1\n\t"
    "global_load_dwordx2 %5, %16, off offset:1280 sc0 sc1\n\t"
    "global_load_dwordx2 %6, %16, off offset:1536 sc0 sc1\n\t"
    "global_load_dwordx2 %7, %16, off offset:1792 sc0 sc1\n\t"
    "global_load_dwordx2 %8, %16, off offset:2048 sc0 sc1\n\t"
    "global_load_dwordx2 %9, %16, off offset:2304 sc0 sc1\n\t"
    "global_load_dwordx2 %10, %16, off offset:2560 sc0 sc1\n\t"
    "global_load_dwordx2 %11, %16, off offset:2816 sc0 sc1\n\t"
    "global_load_dwordx2 %12, %16, off offset:3072 sc0 sc1\n\t"
    "global_load_dwordx2 %13, %16, off offset:3328 sc0 sc1\n\t"
    "global_load_dwordx2 %14, %16, off offset:3584 sc0 sc1\n\t"
    "global_load_dwordx2 %15, %16, off offset:3840 sc0 sc1\n\t"
    "s_waitcnt vmcnt(0)"
    : "=&v"(v0),"=&v"(v1),"=&v"(v2),"=&v"(v3),"=&v"(v4),"=&v"(v5),"=&v"(v6),"=&v"(v7),
      "=&v"(v8),"=&v"(v9),"=&v"(v10),"=&v"(v11),"=&v"(v12),"=&v"(v13),"=&v"(v14),"=&v"(v15)
    : "v"(p) : "memory");
  float s = v0.x+v1.x+v2.x+v3.x+v4.x+v5.x+v6.x+v7.x+v8.x+v9.x+v10.x+v11.x+v12.x+v13.x+v14.x+v15.x;
  float q = v0.y+v1.y+v2.y+v3.y+v4.y+v5.y+v6.y+v7.y+v8.y+v9.y+v10.y+v11.y+v12.y+v13.y+v14.y+v15.y;
  m = s*invn; rs = rsqrtf(q*invn - m*m + 1e-5f);
}

// Coherent load of 8 consecutive 64B k-chunks of one row (offsets 0..448).
__device__ __forceinline__ void ld_co8(const f16* p, f16x8* f){
  asm volatile(
    "global_load_dwordx4 %0, %8, off sc0 sc1\n\t"
    "global_load_dwordx4 %1, %8, off offset:64 sc0 sc1\n\t"
    "global_load_dwordx4 %2, %8, off offset:128 sc0 sc1\n\t"
    "global_load_dwordx4 %3, %8, off offset:192 sc0 sc1\n\t"
    "global_load_dwordx4 %4, %8, off offset:256 sc0 sc1\n\t"
    "global_load_dwordx4 %5, %8, off offset:320 sc0 sc1\n\t"
    "global_load_dwordx4 %6, %8, off offset:384 sc0 sc1\n\t"
    "global_load_dwordx4 %7, %8, off offset:448 sc0 sc1\n\t"
    "s_waitcnt vmcnt(0)"
    : "=&v"(f[0]),"=&v"(f[1]),"=&v"(f[2]),"=&v"(f[3]),
      "=&v"(f[4]),"=&v"(f[5]),"=&v"(f[6]),"=&v"(f[7])
    : "v"(p) : "memory");
}

// ---------------------------------------------------------------------------
__global__ __launch_bounds__(256) void k_transpose_f16(const float* __restrict__ src,
    f16* __restrict__ dst, int K, int N, int dstStride, int dstOff){
  const int n0 = blockIdx.x*32, k0 = blockIdx.y*32, tid = threadIdx.x;
  __shared__ float tl[32][33];
  #pragma unroll
  for (int rep = 0; rep < 4; ++rep){
    int e = rep*256 + tid; int i = e >> 5, j = e & 31;
    int k = k0 + i, n = n0 + j;
    tl[i][j] = (k < K && n < N) ? src[(size_t)k*N + n] : 0.f;
  }
  __syncthreads();
  #pragma unroll
  for (int rep = 0; rep < 4; ++rep){
    int e = rep*256 + tid; int i2 = e & 31, j2 = e >> 5;
    int n = n0 + j2, k = k0 + i2;
    if (k < K && n < N) dst[(size_t)n*dstStride + dstOff + k] = (f16)tl[i2][j2];
  }
}

// ---------------------------------------------------------------------------
__global__ __launch_bounds__(256) void k_prenet(const float* __restrict__ dec,
    const float* __restrict__ w1, const float* __restrict__ w2, f16* __restrict__ cellin){
  const int t = blockIdx.x, tid = threadIdx.x;
  __shared__ float sin_[32][81];
  __shared__ f16   w1T[256][88];
  __shared__ float x1s[32][260];
  __shared__ f16   w2c[256][72];
  __shared__ f16   xo[32][256];
  for (int e = tid; e < 32*80; e += 256){
    int i = e/80, m = e - i*80;
    sin_[i][m] = (t == 0) ? 0.f : dec[(size_t)i*61440 + (size_t)m*768 + (t-1)];
  }
  for (int e = tid; e < 80*256; e += 256){ int m = e >> 8, j = e & 255; w1T[j][m] = (f16)w1[e]; }
  __syncthreads();
  const int j = tid;
  for (int i = 0; i < 32; ++i){
    float a = 0.f;
    #pragma unroll
    for (int m8 = 0; m8 < 10; ++m8){
      f16x8 wvv = *(const f16x8*)&w1T[j][m8*8];
      #pragma unroll
      for (int l = 0; l < 8; ++l) a += (float)wvv[l] * sin_[i][m8*8 + l];
    }
    x1s[i][j] = fmaxf(a, 0.f);
  }
  __syncthreads();
  float acc2[32];
  #pragma unroll
  for (int i = 0; i < 32; ++i) acc2[i] = 0.f;
  for (int c = 0; c < 4; ++c){
    for (int e = tid; e < 64*256; e += 256){
      int kl = e >> 8, jj = e & 255;
      w2c[jj][kl] = (f16)w2[(size_t)(c*64 + kl)*256 + jj];
    }
    __syncthreads();
    f16x8 wv8[8];
    #pragma unroll
    for (int k8 = 0; k8 < 8; ++k8) wv8[k8] = *(const f16x8*)&w2c[j][k8*8];
    for (int i = 0; i < 32; ++i){
      float a = 0.f;
      #pragma unroll
      for (int k8 = 0; k8 < 8; ++k8)
        #pragma unroll
        for (int l = 0; l < 8; ++l) a += (float)wv8[k8][l]*x1s[i][c*64 + k8*8 + l];
      acc2[i] += a;
    }
    __syncthreads();
  }
  for (int i = 0; i < 32; ++i) xo[i][j] = (f16)fmaxf(acc2[i], 0.f);
  __syncthreads();
  for (int e = tid; e < 32*256; e += 256){
    int i = e >> 8, jj = e & 255;
    cellin[((size_t)t*32 + i)*800 + jj] = xo[i][jj];
  }
}

// ---------------------------------------------------------------------------
__global__ __launch_bounds__(256) void k_durfill(const float* __restrict__ dur, f16* __restrict__ cellin){
  const int t = blockIdx.x, tid = threadIdx.x;
  for (int e = tid; e < 32*544; e += 256){
    int b = e / 544, c = e - b*544;
    cellin[((size_t)t*32 + b)*800 + 256 + c] = (f16)dur[(size_t)b*417792 + (size_t)t*544 + c];
  }
}

// ---------------------------------------------------------------------------
__global__ __launch_bounds__(256) void k_ws_report(float* __restrict__ out, int n, float val){
  int i = blockIdx.x*256 + threadIdx.x;
  if (i < n) out[i] = val;
}

// ---------------------------------------------------------------------------
// Pipelined two-layer recurrence. Blocks 0..127 = layer 1 (8 h1-units each),
// blocks 128..255 = layer 2. Each layer: 3 dependent grid-hops per step;
// the two chains overlap (layer 2 runs ~1 step behind via double-buffered h1
// + consumption throttle). Weights in registers (32 B-frags = 128 VGPR/wave,
// legal under launch_bounds(512,1)); wx1 slice in LDS; x-GEMM for t+1 done as
// filler during barrier waits.
// ---------------------------------------------------------------------------
__global__ __launch_bounds__(512, 1) void k_recurrence(
    const f16* __restrict__ cellin, const f16* __restrict__ wxT1,
    const f16* __restrict__ whT1, const f16* __restrict__ w2T,
    f16* __restrict__ H2all, f16* __restrict__ h1buf, f16* __restrict__ h2buf,
    float* __restrict__ sacc, unsigned* __restrict__ ctrs,
    const float* __restrict__ b1v,
    const float* __restrict__ g1, const float* __restrict__ bn1,
    const float* __restrict__ gc1v, const float* __restrict__ bc1v,
    const float* __restrict__ b2v,
    const float* __restrict__ g2, const float* __restrict__ bn2,
    const float* __restrict__ gc2v, const float* __restrict__ bc2v)
{
  const int tid = threadIdx.x, blk = blockIdx.x;
  const int lane = tid & 63, wv = tid >> 6;
  const int r16 = lane & 15, quad = lane >> 4;
  const int part = wv >> 2, pair = wv & 3, rt = pair >> 1, ct = pair & 1;
  const int g_b = ct*2 + (r16 >> 3), u_b = r16 & 7;   // B-frag col decode
  const int u_o = tid >> 5, rb = tid & 31;            // owners (tid<256)
  const int zrow = tid >> 4, zc0 = tid & 15, zc1 = (tid & 15) + 16;
  const int zrt = zrow >> 4, zi = zrow & 15;

  __shared__ f16   swx[3200*8];
  __shared__ float zred[8][16][17];
  __shared__ float zfin[32][33];
  __shared__ float mst[32], vst[32];
  __shared__ float csA[8][32], csQ[8][32];

  f16x8 bfrag[32];

  if (blk < 128){
    // ======================= LAYER 1 =======================
    const int cls = blk & 15, ub0 = blk*8;
    const int colg = (g_b << 10) + ub0 + u_b;
    if (part == 0){
      #pragma unroll
      for (int c = 0; c < 32; ++c)
        bfrag[c] = *(const f16x8*)(whT1 + (size_t)colg*1024 + c*32 + quad*8);
    }
    for (int idx = tid; idx < 3200; idx += 512){
      int l = idx & 15, q = (idx >> 4) & 3, v = idx >> 6;
      int c = v % 25, ctx = v / 25;
      int gg = ctx*2 + (l >> 3), uu = l & 7;
      int cg = (gg << 10) + ub0 + uu;
      *(f16x8*)(swx + idx*8) = *(const f16x8*)(wxT1 + (size_t)cg*800 + c*32 + q*8);
    }
    float pg[4], pb[4], gC = 0.f, bC = 0.f;
    if (tid < 256){
      #pragma unroll
      for (int g = 0; g < 4; ++g){
        int cg = (g << 10) + ub0 + u_o;
        pg[g] = g1[cg]; pb[g] = bn1[cg];
      }
      gC = gc1v[ub0 + u_o]; bC = bc1v[ub0 + u_o];
    }
    const float zb0 = b1v[((zc0 >> 3) << 10) + ub0 + (zc0 & 7)];
    const float zb1 = b1v[((zc1 >> 3) << 10) + ub0 + (zc1 & 7)];
    float c1 = 0.f, o1 = 0.f;
    __syncthreads();
    // prologue: x-GEMM for t=0
    if (part == 1){
      f32x4 a = {0.f,0.f,0.f,0.f};
      const f16* ap = cellin + (size_t)(rt*16 + r16)*800 + quad*8;
      for (int c = 0; c < 25; ++c){
        f16x8 av = *(const f16x8*)(ap + c*32);
        f16x8 bx = *(const f16x8*)(swx + (size_t)(((ct*25 + c)*4 + quad)*16 + r16)*8);
        a = MFMA_F16(av, bx, a);
      }
      #pragma unroll
      for (int reg = 0; reg < 4; ++reg) zred[wv][quad*4 + reg][r16] = a[reg];
    }
    for (int t = 0; t < 768; ++t){
      // --- A1: h1_{t-1} @ wh1 (waves 0-3); x-part already in zred[4..7] ---
      if (t > 0) bar_poll(ctrs, CT_H1, tid, 8u*t);
      __syncthreads();
      if (part == 0){
        f32x4 a = {0.f,0.f,0.f,0.f};
        const f16* hp = h1buf + (size_t)((t+1)&1)*32768 + (size_t)(rt*16 + r16)*1024 + quad*8;
        f16x8 fr[8];
        #pragma unroll
        for (int g4 = 0; g4 < 4; ++g4){
          ld_co8(hp + g4*256, fr);
          #pragma unroll
          for (int kk = 0; kk < 8; ++kk) a = MFMA_F16(fr[kk], bfrag[g4*8 + kk], a);
        }
        #pragma unroll
        for (int reg = 0; reg < 4; ++reg) zred[wv][quad*4 + reg][r16] = a[reg];
      }
      __syncthreads();
      {
        float za  = zred[zrt*2    ][zi][zc0] + zred[4 + zrt*2    ][zi][zc0] + zb0;
        float zbv = zred[zrt*2 + 1][zi][zc0] + zred[4 + zrt*2 + 1][zi][zc0] + zb1;
        zfin[zrow][zc0] = za; zfin[zrow][zc1] = zbv;
        float s = za + zbv, q = za*za + zbv*zbv;
        s += __shfl_down(s, 8); q += __shfl_down(q, 8);
        s += __shfl_down(s, 4); q += __shfl_down(q, 4);
        s += __shfl_down(s, 2); q += __shfl_down(q, 2);
        s += __shfl_down(s, 1); q += __shfl_down(q, 1);
        if ((tid & 15) == 0){
          float* a_ = sacc + (((size_t)t*4 + 0)*NCLS + cls)*64;
          atomicAdd(a_ + 2*zrow, s); atomicAdd(a_ + 2*zrow + 1, q);
        }
      }
      vm_drain(); __syncthreads();
      if (tid == 0) bar_arrive(ctrs + (CT_A1*NCLS + cls)*16);
      // filler: x-GEMM for t+1 (hidden in hop wait)
      if (part == 1 && t < 767){
        f32x4 a = {0.f,0.f,0.f,0.f};
        const f16* ap = cellin + (size_t)(t+1)*25600 + (size_t)(rt*16 + r16)*800 + quad*8;
        for (int c = 0; c < 25; ++c){
          f16x8 av = *(const f16x8*)(ap + c*32);
          f16x8 bx = *(const f16x8*)(swx + (size_t)(((ct*25 + c)*4 + quad)*16 + r16)*8);
          a = MFMA_F16(av, bx, a);
        }
        #pragma unroll
        for (int reg = 0; reg < 4; ++reg) zred[wv][quad*4 + reg][r16] = a[reg];
      }
      bar_poll(ctrs, CT_A1, tid, 8u*(t+1));
      __syncthreads();
      // --- B1: LN1 -> gates -> c1 ---
      if (tid < 32){
        float m, rs;
        ln_stats(sacc + (((size_t)t*4 + 0)*NCLS)*64 + 2*tid, 1.f/4096.f, m, rs);
        mst[tid] = m; vst[tid] = rs;
      }
      __syncthreads();
      if (tid < 256){
        const float m = mst[rb], rs = vst[rb];
        const float ziv = (zfin[rb][u_o]      - m)*rs*pg[0] + pb[0];
        const float zf  = (zfin[rb][8 + u_o]  - m)*rs*pg[1] + pb[1];
        const float zg  = (zfin[rb][16 + u_o] - m)*rs*pg[2] + pb[2];
        const float zo  = (zfin[rb][24 + u_o] - m)*rs*pg[3] + pb[3];
        c1 = sigf(zf)*c1 + sigf(ziv)*tanhf(zg);
        o1 = sigf(zo);
        csA[u_o][rb] = c1; csQ[u_o][rb] = c1*c1;
      }
      __syncthreads();
      if (tid < 32){
        float s = 0.f, q = 0.f;
        #pragma unroll
        for (int u = 0; u < 8; ++u){ s += csA[u][tid]; q += csQ[u][tid]; }
        float* a_ = sacc + (((size_t)t*4 + 1)*NCLS + cls)*64;
        atomicAdd(a_ + 2*tid, s); atomicAdd(a_ + 2*tid + 1, q);
      }
      vm_drain(); __syncthreads();
      if (tid == 0) bar_arrive(ctrs + (CT_B1*NCLS + cls)*16);
      bar_poll(ctrs, CT_B1, tid, 8u*(t+1));
      __syncthreads();
      // --- B1': h1 = sig(o)*tanh(LN(c1)), publish ---
      if (tid < 32){
        float m, rs;
        ln_stats(sacc + (((size_t)t*4 + 1)*NCLS)*64 + 2*tid, 1.f/1024.f, m, rs);
        mst[tid] = m; vst[tid] = rs;
      } else if (t >= 2 && tid < 48){
        const unsigned* p = ctrs + (CT_C*NCLS + (tid - 32))*16;
        while (__hip_atomic_load(p, __ATOMIC_RELAXED, __HIP_MEMORY_SCOPE_AGENT) < 8u*(t-1))
          __builtin_amdgcn_s_sleep(1);
      }
      __syncthreads();
      if (tid < 256){
        float rs = vst[rb];
        float arg = fmaf(fmaf(c1, rs, -mst[rb]*rs), gC, bC);
        float e = exp2f(arg * 2.885390081777927f);
        float h = o1 * fmaf(-2.f, __builtin_amdgcn_rcpf(e + 1.f), 1.f);
        st_wt_f16(h1buf + (size_t)(t&1)*32768 + rb*1024 + ub0 + u_o, (f16)h);
      }
      vm_drain(); __syncthreads();
      if (tid == 0) bar_arrive(ctrs + (CT_H1*NCLS + cls)*16);
    }
  } else {
    // ======================= LAYER 2 =======================
    const int blk2 = blk - 128, cls = blk2 & 15, ub0 = blk2*8;
    const int colg = (g_b << 10) + ub0 + u_b;
    {
      const f16* wsrc = w2T + (size_t)colg*2048 + (part == 0 ? 1024 : 0);
      #pragma unroll
      for (int c = 0; c < 32; ++c)
        bfrag[c] = *(const f16x8*)(wsrc + c*32 + quad*8);
    }
    float pg[4], pb[4], gC = 0.f, bC = 0.f;
    if (tid < 256){
      #pragma unroll
      for (int g = 0; g < 4; ++g){
        int cg = (g << 10) + ub0 + u_o;
        pg[g] = g2[cg]; pb[g] = bn2[cg];
      }
      gC = gc2v[ub0 + u_o]; bC = bc2v[ub0 + u_o];
    }
    const float zb0 = b2v[((zc0 >> 3) << 10) + ub0 + (zc0 & 7)];
    const float zb1 = b2v[((zc1 >> 3) << 10) + ub0 + (zc1 & 7)];
    float c2 = 0.f, o2 = 0.f;
    __syncthreads();
    for (int t = 0; t < 768; ++t){
      // --- A2: z2 = h1_t @ w2x (waves 4-7) + h2_{t-1} @ w2h (waves 0-3) ---
      bar_poll(ctrs, CT_H1, tid, 8u*(t+1));
      if (t > 0 && tid >= 16 && tid < 32){
        const unsigned* p = ctrs + (CT_H2*NCLS + (tid - 16))*16;
        while (__hip_atomic_load(p, __ATOMIC_RELAXED, __HIP_MEMORY_SCOPE_AGENT) < 8u*t)
          __builtin_amdgcn_s_sleep(1);
      }
      __syncthreads();
      {
        f32x4 a = {0.f,0.f,0.f,0.f};
        const f16* hp = (part == 0)
          ? h2buf + (size_t)((t+1)&1)*32768 + (size_t)(rt*16 + r16)*1024 + quad*8
          : h1buf + (size_t)(t&1)*32768     + (size_t)(rt*16 + r16)*1024 + quad*8;
        f16x8 fr[8];
        #pragma unroll
        for (int g4 = 0; g4 < 4; ++g4){
          ld_co8(hp + g4*256, fr);
          #pragma unroll
          for (int kk = 0; kk < 8; ++kk) a = MFMA_F16(fr[kk], bfrag[g4*8 + kk], a);
        }
        #pragma unroll
        for (int reg = 0; reg < 4; ++reg) zred[wv][quad*4 + reg][r16] = a[reg];
      }
      __syncthreads();
      {
        float za  = zred[zrt*2    ][zi][zc0] + zred[4 + zrt*2    ][zi][zc0] + zb0;
        float zbv = zred[zrt*2 + 1][zi][zc0] + zred[4 + zrt*2 + 1][zi][zc0] + zb1;
        zfin[zrow][zc0] = za; zfin[zrow][zc1] = zbv;
        float s = za + zbv, q = za*za + zbv*zbv;
        s += __shfl_down(s, 8); q += __shfl_down(q, 8);
        s += __shfl_down(s, 4); q += __shfl_down(q, 4);
        s += __shfl_down(s, 2); q += __shfl_down(q, 2);
        s += __shfl_down(s, 1); q += __shfl_down(q, 1);
        if ((tid & 15) == 0){
          float* a_ = sacc + (((size_t)t*4 + 2)*NCLS + cls)*64;
          atomicAdd(a_ + 2*zrow, s); atomicAdd(a_ + 2*zrow + 1, q);
        }
      }
      vm_drain(); __syncthreads();
      if (tid == 0)  bar_arrive(ctrs + (CT_A2*NCLS + cls)*16);
      if (tid == 64) bar_arrive(ctrs + (CT_C*NCLS + cls)*16);   // h1_t consumed
      bar_poll(ctrs, CT_A2, tid, 8u*(t+1));
      __syncthreads();
      // --- B2: LN2 -> gates -> c2 ---
      if (tid < 32){
        float m, rs;
        ln_stats(sacc + (((size_t)t*4 + 2)*NCLS)*64 + 2*tid, 1.f/4096.f, m, rs);
        mst[tid] = m; vst[tid] = rs;
      }
      __syncthreads();
      if (tid < 256){
        const float m = mst[rb], rs = vst[rb];
        const float ziv = (zfin[rb][u_o]      - m)*rs*pg[0] + pb[0];
        const float zf  = (zfin[rb][8 + u_o]  - m)*rs*pg[1] + pb[1];
        const float zg  = (zfin[rb][16 + u_o] - m)*rs*pg[2] + pb[2];
        const float zo  = (zfin[rb][24 + u_o] - m)*rs*pg[3] + pb[3];
        c2 = sigf(zf)*c2 + sigf(ziv)*tanhf(zg);
        o2 = sigf(zo);
        csA[u_o][rb] = c2; csQ[u_o][rb] = c2*c2;
      }
      __syncthreads();
      if (tid < 32){
        float s = 0.f, q = 0.f;
        #pragma unroll
        for (int u = 0; u < 8; ++u){ s += csA[u][tid]; q += csQ[u][tid]; }
        float* a_ = sacc + (((size_t)t*4 + 3)*NCLS + cls)*64;
        atomicAdd(a_ + 2*tid, s); atomicAdd(a_ + 2*tid + 1, q);
      }
      vm_drain(); __syncthreads();
      if (tid == 0) bar_arrive(ctrs + (CT_B2*NCLS + cls)*16);
      bar_poll(ctrs, CT_B2, tid, 8u*(t+1));
      __syncthreads();
      // --- B2': h2 publish (+ H2all for projection) ---
      if (tid < 32){
        float m, rs;
        ln_stats(sacc + (((size_t)t*4 + 3)*NCLS)*64 + 2*tid, 1.f/1024.f, m, rs);
        mst[tid] = m; vst[tid] = rs;
      }
      __syncthreads();
      if (tid < 256){
        float rs = vst[rb];
        float arg = fmaf(fmaf(c2, rs, -mst[rb]*rs), gC, bC);
        float e = exp2f(arg * 2.885390081777927f);
        float h = o2 * fmaf(-2.f, __builtin_amdgcn_rcpf(e + 1.f), 1.f);
        st_wt_f16(h2buf + (size_t)(t&1)*32768 + rb*1024 + ub0 + u_o, (f16)h);
        st_wt_f16(H2all + (size_t)(t+1)*32768 + rb*1024 + ub0 + u_o, (f16)h);
      }
      vm_drain(); __syncthreads();
      if (tid == 0) bar_arrive(ctrs + (CT_H2*NCLS + cls)*16);
    }
  }
}

// ---------------------------------------------------------------------------
__global__ __launch_bounds__(256) void k_proj(const f16* __restrict__ H2all, const f16* __restrict__ cellin,
    const f16* __restrict__ projT, const float* __restrict__ projb, float* __restrict__ out){
  const int t = blockIdx.x, tid = threadIdx.x;
  const int lane = tid & 63, wv = tid >> 6;
  const int r16 = lane & 15, quad = lane >> 4;
  __shared__ float pred[4][32][84];
  f32x4 acc[2][5] = {};
  const f16* H2 = H2all + (size_t)(t+1)*32768;
  const f16* CI = cellin + (size_t)t*32*800;
  const int kbeg = wv*13;
  const int kend = (wv == 3) ? 49 : (kbeg + 13);
  for (int ks = kbeg; ks < kend; ++ks){
    const int k0 = ks*32 + quad*8;
    f16x8 a0, a1;
    if (ks < 32){
      a0 = *(const f16x8*)(H2 + r16*1024 + k0);
      a1 = *(const f16x8*)(H2 + (16+r16)*1024 + k0);
    } else {
      a0 = *(const f16x8*)(CI + r16*800 + 256 + (k0 - 1024));
      a1 = *(const f16x8*)(CI + (16+r16)*800 + 256 + (k0 - 1024));
    }
    f16x8 bf[5];
    #pragma unroll
    for (int nt = 0; nt < 5; ++nt)
      bf[nt] = *(const f16x8*)(projT + (size_t)(nt*16 + r16)*1568 + k0);
    #pragma unroll
    for (int nt = 0; nt < 5; ++nt){
      acc[0][nt] = MFMA_F16(a0, bf[nt], acc[0][nt]);
      acc[1][nt] = MFMA_F16(a1, bf[nt], acc[1][nt]);
    }
  }
  #pragma unroll
  for (int mt = 0; mt < 2; ++mt)
    #pragma unroll
    for (int nt = 0; nt < 5; ++nt)
      #pragma unroll
      for (int reg = 0; reg < 4; ++reg)
        pred[wv][mt*16 + quad*4 + reg][nt*16 + r16] = acc[mt][nt][reg];
  __syncthreads();
  for (int e = tid; e < 2560; e += 256){
    int m = e >> 5, b = e & 31;
    float v = pred[0][b][m] + pred[1][b][m] + pred[2][b][m] + pred[3][b][m] + projb[m];
    out[(size_t)b*61440 + (size_t)m*768 + t] = v;
  }
}

// ---------------------------------------------------------------------------
extern "C" void kernel_launch(void* const* d_in, const int* in_sizes, int n_in,
                              void* d_out, int out_size, void* d_ws, size_t ws_size,
                              hipStream_t stream)
{
  const float* duration = (const float*)d_in[0];
  const float* decoder  = (const float*)d_in[1];
  const float* pre_w1   = (const float*)d_in[3];
  const float* pre_w2   = (const float*)d_in[4];
  const float* rnn1_wx  = (const float*)d_in[5];
  const float* rnn1_wh  = (const float*)d_in[6];
  const float* rnn1_b   = (const float*)d_in[7];
  const float* rnn1_g   = (const float*)d_in[8];
  const float* rnn1_bn  = (const float*)d_in[9];
  const float* rnn1_gc  = (const float*)d_in[10];
  const float* rnn1_bc  = (const float*)d_in[11];
  const float* rnn2_wx  = (const float*)d_in[12];
  const float* rnn2_wh  = (const float*)d_in[13];
  const float* rnn2_b   = (const float*)d_in[14];
  const float* rnn2_g   = (const float*)d_in[15];
  const float* rnn2_bn  = (const float*)d_in[16];
  const float* rnn2_gc  = (const float*)d_in[17];
  const float* rnn2_bc  = (const float*)d_in[18];
  const float* proj_w   = (const float*)d_in[19];
  const float* proj_b   = (const float*)d_in[20];
  float* out = (float*)d_out;

  char* w = (char*)d_ws;
  f16* cellin = (f16*)w;      w += (size_t)24576*800*2;
  f16* wxT1   = (f16*)w;      w += (size_t)4096*800*2;
  f16* whT1   = (f16*)w;      w += (size_t)4096*1024*2;
  f16* w2T    = (f16*)w;      w += (size_t)4096*2048*2;
  f16* projT  = (f16*)w;      w += 262144;
  f16* H2all  = (f16*)w;      w += (size_t)769*32768*2;
  f16* h1buf  = (f16*)w;      w += 131072;   // 2 slots x 32x1024 f16
  f16* h2buf  = (f16*)w;      w += 131072;
  float* sacc = (float*)w;    w += (size_t)768*4*16*64*4;
  unsigned* ctrs = (unsigned*)w; w += 8192;
  const size_t need = (size_t)((char*)w - (char*)d_ws);
  if (ws_size < need){
    k_ws_report<<<(out_size + 255)/256, 256, 0, stream>>>(out, out_size, (float)(ws_size >> 20));
    return;
  }

  (void)hipMemsetAsync(sacc, 0, (size_t)768*4*16*64*4, stream);
  (void)hipMemsetAsync(ctrs, 0, 8192, stream);
  (void)hipMemsetAsync(h1buf, 0, 131072, stream);
  (void)hipMemsetAsync(h2buf, 0, 131072, stream);

  k_transpose_f16<<<dim3(4096/32, 25), 256, 0, stream>>>(rnn1_wx, wxT1, 800, 4096, 800, 0);
  k_transpose_f16<<<dim3(4096/32, 32), 256, 0, stream>>>(rnn1_wh, whT1, 1024, 4096, 1024, 0);
  k_transpose_f16<<<dim3(4096/32, 32), 256, 0, stream>>>(rnn2_wx, w2T, 1024, 4096, 2048, 0);
  k_transpose_f16<<<dim3(4096/32, 32), 256, 0, stream>>>(rnn2_wh, w2T, 1024, 4096, 2048, 1024);
  k_transpose_f16<<<dim3(3, 49), 256, 0, stream>>>(proj_w, projT, 1568, 80, 1568, 0);
  k_prenet<<<768, 256, 0, stream>>>(decoder, pre_w1, pre_w2, cellin);
  k_durfill<<<768, 256, 0, stream>>>(duration, cellin);
  k_recurrence<<<256, 512, 0, stream>>>(cellin, wxT1, whT1, w2T, H2all, h1buf, h2buf, sacc, ctrs,
      rnn1_b, rnn1_g, rnn1_bn, rnn1_gc, rnn1_bc,
      rnn2_b, rnn2_g, rnn2_bn, rnn2_gc, rnn2_bc);
  k_proj<<<768, 256, 0, stream>>>(H2all, cellin, projT, proj_b, out);
}